// Round 14
// baseline (839.434 us; speedup 1.0000x reference)
//
#include <hip/hip_runtime.h>
#include <cstdint>

typedef long long ll;
typedef __bf16 bf16x8 __attribute__((ext_vector_type(8)));
typedef float f32x4 __attribute__((ext_vector_type(4)));
typedef unsigned int u32x4 __attribute__((ext_vector_type(4)));

#define NB 8
#define NT 12
#define NF 64
#define HWSZ 4096
#define I2H_T ((ll)NB * 4096 * 192)
#define I2F_T ((ll)NB * 4096 * 32)

struct alignas(8)  bh4 { __bf16 h[4]; };
struct alignas(16) bh8 { __bf16 h[8]; };

static __device__ inline f32x4 mfma16(bf16x8 a, bf16x8 b, f32x4 c) {
  return __builtin_amdgcn_mfma_f32_16x16x32_bf16(a, b, c, 0, 0, 0);
}
static __device__ inline bf16x8 ld8(const __bf16* p) {
  u32x4 u = *(const u32x4*)p;
  return __builtin_bit_cast(bf16x8, u);
}
static __device__ inline void st4(__bf16* p, float a0, float a1, float a2, float a3) {
  bh4 t; t.h[0] = (__bf16)a0; t.h[1] = (__bf16)a1; t.h[2] = (__bf16)a2; t.h[3] = (__bf16)a3;
  *(bh4*)p = t;
}
static __device__ inline float lky(float a) { return a >= 0.f ? a : 0.2f * a; }

// XCD-chunked swizzle (grid divisible by 8): neighbors share an XCD L2.
static __device__ inline int swz_bid() {
  int bid = blockIdx.x;
  return ((gridDim.x & 7) == 0) ? (bid & 7) * (gridDim.x >> 3) + (bid >> 3) : bid;
}

// Step-kernel decode with y-octile XCD affinity.
static __device__ inline void step_decode(int& b, int& y, int& xh) {
  int bid = blockIdx.x;
  int oct = bid & 7, s = bid >> 3;
  b = s >> 4;
  int r = s & 15;
  y = oct * 8 + (r >> 1);
  xh = r & 1;
}

// Stage one row of a 64-ch NHWC bf16 map into LDS [g8][W][8] (full channels).
template<int W, int HALO>
static __device__ void stage8(__bf16* dst, const __bf16* grow) {
  int tid = threadIdx.x;
  u32x4 zz = {0u, 0u, 0u, 0u};
  #pragma unroll
  for (int it = 0; it < 2; ++it) {
    int i = tid + it * 256;
    int xr = i >> 3, g = i & 7, xi = xr + HALO;
    u32x4 v = zz;
    if (grow) v = *(const u32x4*)(grow + xr * 64 + g * 8);
    *(u32x4*)(dst + (g * W + xi) * 8) = v;
  }
  if (tid < 16 * HALO) {
    int h = tid >> 3, g = tid & 7;
    int xi = (h < HALO) ? h : 64 + h;
    *(u32x4*)(dst + (g * W + xi) * 8) = zz;
  }
}

// ---------------------------------------------------------------------------
// Weight pre-transform: bf16 fragment-friendly layouts.
__global__ __launch_bounds__(256) void k_prep(
    const float* __restrict__ Wd, const float* __restrict__ Wc,
    const float* __restrict__ Wi, const float* __restrict__ Wh,
    const float* __restrict__ Wfl, const float* __restrict__ Wret,
    __bf16* __restrict__ Adown, __bf16* __restrict__ Ai2h,
    __bf16* __restrict__ Afi, __bf16* __restrict__ Afh,
    __bf16* __restrict__ Afl, __bf16* __restrict__ Aret) {
  int n = blockIdx.x * 256 + threadIdx.x;
  if (n < 147456) {                            // Adown[oc][k]
    Adown[n] = (__bf16)Wd[n];
  } else if (n < 258048) {                     // Ai2h[tap][o192][c64]
    int i = n - 147456;
    int tap = i / 12288, o = (i % 12288) / 64, c = i % 64;
    Ai2h[i] = (__bf16)Wc[(o * 64 + c) * 9 + tap];
  } else if (n < 309248) {                     // Afi[tap][o32][c64]
    int i = n - 258048;
    int tap = i / 2048, o = (i % 2048) / 64, c = i % 64;
    Afi[i] = (__bf16)Wi[(o * 64 + c) * 25 + tap];
  } else if (n < 360448) {                     // Afh[tap][o32][c64]
    int i = n - 309248;
    int tap = i / 2048, o = (i % 2048) / 64, c = i % 64;
    Afh[i] = (__bf16)Wh[(o * 64 + c) * 25 + tap];
  } else if (n < 373248) {                     // Afl[tap][o16 pad][c32]
    int i = n - 360448;
    int tap = i / 512, o = (i % 512) / 32, c = i % 32;
    Afl[i] = (__bf16)(o < 10 ? Wfl[(o * 32 + c) * 25 + tap] : 0.f);
  } else if (n < 434688) {                     // Aret[o192][c320]
    Aret[n - 373248] = (__bf16)Wret[n - 373248];
  }
}

// ---------------------------------------------------------------------------
// Downsample conv as MFMA implicit GEMM. (b,y,zQ); zQ splits M=768 into 4.
__global__ __launch_bounds__(256) void k_down(
    const float* __restrict__ x, const __bf16* __restrict__ Adown,
    const float* __restrict__ bd, __bf16* __restrict__ seq) {
  __shared__ __bf16 smd[6240];
  int bi = swz_bid();
  int zQ = bi & 3, y = (bi >> 2) & 63, b = bi >> 8;
  int tid = threadIdx.x;
  for (int i = tid; i < 6240; i += 256) {
    int ic = i / 520, rem = i % 520, ky = rem / 130, xi = rem % 130;
    int ix = xi - 1, iy = 2 * y - 1 + ky;
    float v = (ix >= 0 && ix < 128 && iy >= 0 && iy < 128)
                  ? x[(((ll)(b * 12 + ic) * 128 + iy) << 7) + ix] : 0.f;
    smd[i] = (__bf16)v;
  }
  __syncthreads();
  int wv = __builtin_amdgcn_readfirstlane(tid >> 6);
  int lane = tid & 63, q = lane >> 4, lr = lane & 15;
  int px = wv * 16 + lr;
  f32x4 zv = {0.f, 0.f, 0.f, 0.f};
  f32x4 acc[12];
  #pragma unroll
  for (int mt = 0; mt < 12; ++mt) acc[mt] = zv;

  for (int ks = 0; ks < 6; ++ks) {
    int k0 = ks * 32 + q * 8;
    int ic = k0 >> 4, ky0 = (k0 >> 2) & 3;
    const __bf16* rp = smd + (ic * 4 + ky0) * 130 + 2 * px;
    bh8 bb;
    #pragma unroll
    for (int j = 0; j < 8; ++j)
      bb.h[j] = rp[(j >> 2) * 130 + (j & 3)];
    bf16x8 bfr = __builtin_bit_cast(bf16x8, bb);
    #pragma unroll
    for (int mt = 0; mt < 12; ++mt) {
      bf16x8 afr = ld8(Adown + ((ll)(zQ * 192 + mt * 16 + lr) * 192 + k0));
      acc[mt] = mfma16(afr, bfr, acc[mt]);
    }
  }
  #pragma unroll
  for (int mt = 0; mt < 12; ++mt) {
    int t_idx = zQ * 3 + (mt >> 2);
    int f0 = (mt & 3) * 16 + q * 4;
    float v[4];
    #pragma unroll
    for (int r = 0; r < 4; ++r)
      v[r] = lky(acc[mt][r] + bd[zQ * 192 + mt * 16 + q * 4 + r]);
    st4(seq + (((ll)(t_idx * NB + b) * 4096 + y * 64 + px) * 64 + f0),
        v[0], v[1], v[2], v[3]);
  }
}

// ---------------------------------------------------------------------------
// i2h 3x3 conv, A staged per-tap in double-buffered LDS (R10 version).
__global__ __launch_bounds__(256, 2) void k_i2h4(
    const __bf16* __restrict__ in0, const __bf16* __restrict__ A,
    const float* __restrict__ bc, __bf16* __restrict__ out0) {
  __shared__ __align__(16) __bf16 smI[6 * 8 * 67 * 8];
  __shared__ __align__(16) __bf16 smA[2][96 * 64];
  int bi_ = swz_bid();
  int yg = bi_ & 15, och = (bi_ >> 4) & 1, tb = bi_ >> 5;
  int y0 = yg * 4;
  const __bf16* base = in0 + (ll)tb * (4096 * 64);
  const __bf16* Ab = A + ((ll)och * 96) * 64;
  int tid = threadIdx.x;
  u32x4 ar[3];
  auto loadA = [&](int tap) {
    #pragma unroll
    for (int it = 0; it < 3; ++it) {
      int j = it * 256 + tid;
      ar[it] = *(const u32x4*)(Ab + (ll)tap * (192 * 64) + j * 8);
    }
  };
  auto writeA = [&](int buf) {
    #pragma unroll
    for (int it = 0; it < 3; ++it) {
      int j = it * 256 + tid;
      int oc = j >> 3, g = j & 7;
      *(u32x4*)(smA[buf] + oc * 64 + ((g ^ (oc & 7)) * 8)) = ar[it];
    }
  };
  loadA(0);
  #pragma unroll
  for (int s = 0; s < 6; ++s) {
    int yr = y0 - 1 + s;
    stage8<67, 1>(smI + s * (8 * 67 * 8),
                  (yr >= 0 && yr < 64) ? base + (ll)yr * 64 * 64 : nullptr);
  }
  writeA(0);
  __syncthreads();

  int wv = __builtin_amdgcn_readfirstlane(tid >> 6);
  int lane = tid & 63, q = lane >> 4, lr = lane & 15;
  int mh = wv & 1, rg = wv >> 1;
  f32x4 zv = {0.f, 0.f, 0.f, 0.f};
  f32x4 acc[3][8];
  #pragma unroll
  for (int mt = 0; mt < 3; ++mt)
    #pragma unroll
    for (int nt = 0; nt < 8; ++nt) acc[mt][nt] = zv;

  for (int tap = 0; tap < 9; ++tap) {
    if (tap < 8) loadA(tap + 1);
    int ky = tap / 3, kx = tap % 3;
    const __bf16* Ax = smA[tap & 1];
    #pragma unroll
    for (int ks = 0; ks < 2; ++ks) {
      bf16x8 afr[3];
      #pragma unroll
      for (int mt = 0; mt < 3; ++mt) {
        int oc = mh * 48 + mt * 16 + lr;
        afr[mt] = ld8(Ax + oc * 64 + (((ks * 4 + q) ^ (lr & 7)) * 8));
      }
      bf16x8 bfr[8];
      #pragma unroll
      for (int rl = 0; rl < 2; ++rl)
        #pragma unroll
        for (int nx = 0; nx < 4; ++nx) {
          int s = rg * 2 + rl + ky;
          bfr[rl * 4 + nx] =
              ld8(smI + ((s * 8 + ks * 4 + q) * 67 + nx * 16 + lr + kx) * 8);
        }
      #pragma unroll
      for (int mt = 0; mt < 3; ++mt)
        #pragma unroll
        for (int nt = 0; nt < 8; ++nt)
          acc[mt][nt] = mfma16(afr[mt], bfr[nt], acc[mt][nt]);
    }
    if (tap < 8) writeA((tap + 1) & 1);
    __syncthreads();
  }

  #pragma unroll
  for (int rl = 0; rl < 2; ++rl)
    #pragma unroll
    for (int nx = 0; nx < 4; ++nx) {
      int row = y0 + rg * 2 + rl, px = nx * 16 + lr;
      __bf16* op = out0 + ((ll)tb * 4096 + row * 64 + px) * 192;
      #pragma unroll
      for (int mt = 0; mt < 3; ++mt) {
        int oc0 = och * 96 + mh * 48 + mt * 16 + q * 4;
        f32x4 a = acc[mt][rl * 4 + nx];
        st4(op + oc0, a[0] + bc[oc0], a[1] + bc[oc0 + 1],
                      a[2] + bc[oc0 + 2], a[3] + bc[oc0 + 3]);
      }
    }
}

// ---------------------------------------------------------------------------
// Batched i2f 5x5 (no bias), R10 version.
__global__ __launch_bounds__(256, 2) void k_i2fb(
    const __bf16* __restrict__ in0, const __bf16* __restrict__ A,
    __bf16* __restrict__ out0) {
  __shared__ __align__(16) __bf16 smI[8 * 8 * 69 * 8];
  __shared__ __align__(16) __bf16 smA[2][32 * 64];
  float* red = (float*)smI;
  int bi_ = swz_bid();
  int yg = bi_ & 15, tb = bi_ >> 4;
  int y0 = yg * 4;
  const __bf16* base = in0 + (ll)tb * (4096 * 64);
  int tid = threadIdx.x;
  u32x4 ar;
  auto loadA = [&](int tap) { ar = *(const u32x4*)(A + (ll)tap * 2048 + tid * 8); };
  auto writeA = [&](int buf) {
    int oc = tid >> 3, g = tid & 7;
    *(u32x4*)(smA[buf] + oc * 64 + ((g ^ (oc & 7)) * 8)) = ar;
  };
  loadA(0);
  #pragma unroll
  for (int s = 0; s < 8; ++s) {
    int yr = y0 - 2 + s;
    stage8<69, 2>(smI + s * (8 * 69 * 8),
                  (yr >= 0 && yr < 64) ? base + (ll)yr * 64 * 64 : nullptr);
  }
  writeA(0);
  __syncthreads();

  int wv = __builtin_amdgcn_readfirstlane(tid >> 6);
  int lane = tid & 63, q = lane >> 4, lr = lane & 15;
  int rg = wv & 1, ksh = wv >> 1;
  f32x4 zv = {0.f, 0.f, 0.f, 0.f};
  f32x4 acc[2][8];
  #pragma unroll
  for (int mt = 0; mt < 2; ++mt)
    #pragma unroll
    for (int nt = 0; nt < 8; ++nt) acc[mt][nt] = zv;

  for (int tap = 0; tap < 25; ++tap) {
    if (tap < 24) loadA(tap + 1);
    int ky = tap / 5, kx = tap % 5;
    const __bf16* Ax = smA[tap & 1];
    bf16x8 afr[2];
    #pragma unroll
    for (int mt = 0; mt < 2; ++mt) {
      int oc = mt * 16 + lr;
      afr[mt] = ld8(Ax + oc * 64 + (((ksh * 4 + q) ^ (lr & 7)) * 8));
    }
    bf16x8 bfr[8];
    #pragma unroll
    for (int rl = 0; rl < 2; ++rl)
      #pragma unroll
      for (int nx = 0; nx < 4; ++nx) {
        int s = rg * 2 + rl + ky;
        bfr[rl * 4 + nx] =
            ld8(smI + ((s * 8 + ksh * 4 + q) * 69 + nx * 16 + lr + kx) * 8);
      }
    #pragma unroll
    for (int mt = 0; mt < 2; ++mt)
      #pragma unroll
      for (int nt = 0; nt < 8; ++nt)
        acc[mt][nt] = mfma16(afr[mt], bfr[nt], acc[mt][nt]);
    if (tap < 24) writeA((tap + 1) & 1);
    __syncthreads();
  }

  if (ksh == 1) {
    #pragma unroll
    for (int mt = 0; mt < 2; ++mt)
      #pragma unroll
      for (int rl = 0; rl < 2; ++rl)
        #pragma unroll
        for (int nx = 0; nx < 4; ++nx) {
          int row_l = rg * 2 + rl, px = nx * 16 + lr;
          int oc = mt * 16 + q * 4;
          f32x4 a = acc[mt][rl * 4 + nx];
          #pragma unroll
          for (int r = 0; r < 4; ++r)
            red[(row_l * 64 + px) * 33 + oc + r] = a[r];
        }
  }
  __syncthreads();
  if (ksh == 0) {
    #pragma unroll
    for (int mt = 0; mt < 2; ++mt)
      #pragma unroll
      for (int rl = 0; rl < 2; ++rl)
        #pragma unroll
        for (int nx = 0; nx < 4; ++nx) {
          int row_l = rg * 2 + rl, px = nx * 16 + lr;
          int oc0 = mt * 16 + q * 4;
          f32x4 a = acc[mt][rl * 4 + nx];
          float v[4];
          #pragma unroll
          for (int r = 0; r < 4; ++r)
            v[r] = a[r] + red[(row_l * 64 + px) * 33 + oc0 + r];
          st4(out0 + ((ll)tb * 4096 + (y0 + row_l) * 64 + px) * 32 + oc0,
              v[0], v[1], v[2], v[3]);
        }
  }
}

// ---------------------------------------------------------------------------
// Step-phase device functions.
#define H2F_SMEM_BYTES 23680
#define FWR_SMEM_BYTES (25344 + 2176)

static __device__ void dev_h2f(char* smraw, int t0,
    const __bf16* __restrict__ hb, const __bf16* __restrict__ A,
    const float* __restrict__ bi, const float* __restrict__ bh,
    const __bf16* __restrict__ i2f_t, __bf16* __restrict__ f1buf,
    int b, int y, int xh) {
  __bf16* smI = (__bf16*)smraw;
  float* red = (float*)smraw;
  int x0 = xh * 32;
  int tid = threadIdx.x;
  int wv = __builtin_amdgcn_readfirstlane(tid >> 6);
  int lane = tid & 63, q = lane >> 4, lr = lane & 15;

  int pxl_e = tid >> 3, oc0_e = (tid & 7) * 4;
  bh4 iv = *(const bh4*)(i2f_t + ((ll)(b * 64 + y) * 64 + x0 + pxl_e) * 32 + oc0_e);

  bf16x8 cur[2][2], nxt[2][2];
  auto loadAt = [&](int tap, bf16x8 a[2][2]) {
    #pragma unroll
    for (int ks = 0; ks < 2; ++ks)
      #pragma unroll
      for (int mt = 0; mt < 2; ++mt)
        a[ks][mt] = ld8(A + ((ll)(tap * 32 + mt * 16 + lr) * 64 + ks * 32 + q * 8));
  };
  loadAt(wv, cur);

  u32x4 zz = {0u, 0u, 0u, 0u};
  for (int i = tid; i < 5 * 296; i += 256) {
    int s = i / 296, rem = i % 296, xi = rem >> 3, g = rem & 7;
    int yr = y - 2 + s, xg = x0 - 2 + xi;
    u32x4 v = zz;
    if (!t0 && yr >= 0 && yr < 64 && xg >= 0 && xg < 64)
      v = *(const u32x4*)(hb + ((ll)(b * 64 + yr) * 64 + xg) * 64 + g * 8);
    *(u32x4*)(smI + ((s * 8 + g) * 37 + xi) * 8) = v;
  }
  __syncthreads();

  f32x4 zv = {0.f, 0.f, 0.f, 0.f};
  f32x4 acc[2][2];
  #pragma unroll
  for (int mt = 0; mt < 2; ++mt)
    #pragma unroll
    for (int nx = 0; nx < 2; ++nx) acc[mt][nx] = zv;

  #pragma unroll
  for (int j = 0; j < 7; ++j) {
    int tap = 4 * j + wv;
    if (tap < 25) {
      if (tap + 4 < 25) loadAt(tap + 4, nxt);
      int ky = tap / 5, kx = tap % 5;
      #pragma unroll
      for (int ks = 0; ks < 2; ++ks) {
        bf16x8 bfr[2];
        #pragma unroll
        for (int nx = 0; nx < 2; ++nx)
          bfr[nx] = ld8(smI + ((ky * 8 + ks * 4 + q) * 37 + nx * 16 + lr + kx) * 8);
        #pragma unroll
        for (int mt = 0; mt < 2; ++mt)
          #pragma unroll
          for (int nx = 0; nx < 2; ++nx)
            acc[mt][nx] = mfma16(cur[ks][mt], bfr[nx], acc[mt][nx]);
      }
      #pragma unroll
      for (int ks = 0; ks < 2; ++ks)
        #pragma unroll
        for (int mt = 0; mt < 2; ++mt) cur[ks][mt] = nxt[ks][mt];
    }
  }
  __syncthreads();

  #pragma unroll
  for (int mt = 0; mt < 2; ++mt)
    #pragma unroll
    for (int nx = 0; nx < 2; ++nx) {
      int pxl = nx * 16 + lr, oc = mt * 16 + q * 4;
      f32x4 a = acc[mt][nx];
      #pragma unroll
      for (int r = 0; r < 4; ++r)
        red[wv * 1056 + pxl * 33 + oc + r] = a[r];
    }
  __syncthreads();

  float v[4];
  #pragma unroll
  for (int r = 0; r < 4; ++r) {
    float s = red[0 * 1056 + pxl_e * 33 + oc0_e + r] + red[1 * 1056 + pxl_e * 33 + oc0_e + r] +
              red[2 * 1056 + pxl_e * 33 + oc0_e + r] + red[3 * 1056 + pxl_e * 33 + oc0_e + r];
    v[r] = lky(s + (float)iv.h[r] + bi[oc0_e + r] + bh[oc0_e + r]);
  }
  st4(f1buf + ((ll)(b * 64 + y) * 64 + x0 + pxl_e) * 32 + oc0_e, v[0], v[1], v[2], v[3]);
}

// fwr with GATE-BLOCK M-split (R13) + 4-wave flow conv (px-half x tap-parity).
static __device__ void dev_fwr(char* smraw, int t0,
    const __bf16* __restrict__ f1buf, const __bf16* __restrict__ Afl,
    const float* __restrict__ bfl, const __bf16* __restrict__ hb,
    const __bf16* __restrict__ Aret, const float* __restrict__ br,
    const __bf16* __restrict__ i2h_t, const float* __restrict__ hprevf,
    float* __restrict__ outp, ll osb, __bf16* __restrict__ hbc,
    int b, int y, int xh) {
  float* flows = (float*)(smraw + 25344);
  __bf16* f1l = (__bf16*)smraw;
  __bf16* wrp = (__bf16*)smraw;
  float* scratch = (float*)smraw;          // overlays f1l after flow reads
  int x0 = xh * 32;
  int tid = threadIdx.x;
  int wv = __builtin_amdgcn_readfirstlane(tid >> 6);
  int lane = tid & 63, q = lane >> 4, lr = lane & 15;

  // hoisted gate inputs (cold -> issue first)
  int f0w = wv * 16 + q * 4;
  bh4 irv[2], iuv[2], imv[2];
  float h04[2][4];
  #pragma unroll
  for (int nt = 0; nt < 2; ++nt) {
    int xg = x0 + nt * 16 + lr;
    const __bf16* ih = i2h_t + ((ll)(b * 64 + y) * 64 + xg) * 192;
    irv[nt] = *(const bh4*)(ih + f0w);
    iuv[nt] = *(const bh4*)(ih + 64 + f0w);
    imv[nt] = *(const bh4*)(ih + 128 + f0w);
    const float* hp = hprevf + (ll)b * osb + y * 64 + xg;
    #pragma unroll
    for (int r = 0; r < 4; ++r)
      h04[nt][r] = t0 ? 0.f : hp[(ll)(f0w + r) << 12];
  }

  u32x4 zz = {0u, 0u, 0u, 0u};
  for (int i = tid; i < 5 * 148; i += 256) {
    int s = i / 148, rem = i % 148, xi = rem >> 2, g = rem & 3;
    int yr = y - 2 + s, xg = x0 - 2 + xi;
    u32x4 v = zz;
    if (yr >= 0 && yr < 64 && xg >= 0 && xg < 64)
      v = *(const u32x4*)(f1buf + ((ll)(b * 64 + yr) * 64 + xg) * 32 + g * 8);
    *(u32x4*)(f1l + ((s * 4 + g) * 37 + xi) * 8) = v;
  }
  __syncthreads();

  // flow conv on ALL 4 waves: px-half = wv&1, tap-parity = wv>>1
  {
    int xhf = wv & 1, kp = wv >> 1;
    f32x4 acc1 = {0.f, 0.f, 0.f, 0.f};
    for (int tap = kp; tap < 25; tap += 2) {
      int ky = tap / 5, kx = tap % 5;
      bf16x8 bfr = ld8(f1l + ((ky * 4 + q) * 37 + xhf * 16 + lr + kx) * 8);
      bf16x8 afr = ld8(Afl + ((ll)(tap * 16 + lr) * 32 + q * 8));
      acc1 = mfma16(afr, bfr, acc1);
    }
    __syncthreads();                       // f1l reads done (all waves)
    if (kp == 1) {
      #pragma unroll
      for (int r = 0; r < 4; ++r)
        scratch[(xhf * 16 + lr) * 17 + q * 4 + r] = acc1[r];
    }
    __syncthreads();
    if (kp == 0) {
      #pragma unroll
      for (int r = 0; r < 4; ++r) {
        int oc = q * 4 + r;
        flows[(xhf * 16 + lr) * 17 + oc] =
            acc1[r] + scratch[(xhf * 16 + lr) * 17 + oc] + (oc < 10 ? bfl[oc] : 0.f);
      }
    }
  }
  __syncthreads();

  // issue first Aret fragments before warp so L2 latency hides under it
  bf16x8 cR[3], nR[3];
  auto loadAr = [&](int ks, bf16x8* a) {
    #pragma unroll
    for (int mt = 0; mt < 3; ++mt)
      a[mt] = ld8(Aret + ((ll)(mt * 64 + wv * 16 + lr) * 320 + ks * 32 + q * 8));
  };
  loadAr(0, cR);

  {
    int pxl = tid & 31, cg = tid >> 5;
    int xw = x0 + pxl;
    const __bf16* hbb = hb + ((ll)b << 18);
    #pragma unroll
    for (int l = 0; l < 5; ++l) {
      bh8 ov;
      if (t0) {
        #pragma unroll
        for (int i = 0; i < 8; ++i) ov.h[i] = (__bf16)0.f;
      } else {
        float fx = flows[pxl * 17 + 2 * l];
        float fy = flows[pxl * 17 + 2 * l + 1];
        float pxf = (float)xw - fx, pyf = (float)y - fy;
        float x0f = floorf(pxf), y0f = floorf(pyf);
        int xx0 = (int)x0f, yy0 = (int)y0f, xx1 = xx0 + 1, yy1 = yy0 + 1;
        float dx = pxf - x0f, dy = pyf - y0f;
        bool vx0 = xx0 >= 0 && xx0 <= 63, vx1 = xx1 >= 0 && xx1 <= 63;
        bool vy0 = yy0 >= 0 && yy0 <= 63, vy1 = yy1 >= 0 && yy1 <= 63;
        float wA = (vx0 && vy0) ? (1.f - dx) * (1.f - dy) : 0.f;
        float wB = (vx0 && vy1) ? (1.f - dx) * dy : 0.f;
        float wC = (vx1 && vy0) ? dx * (1.f - dy) : 0.f;
        float wD = (vx1 && vy1) ? dx * dy : 0.f;
        int cx0 = min(max(xx0, 0), 63), cx1 = min(max(xx1, 0), 63);
        int cy0 = min(max(yy0, 0), 63), cy1 = min(max(yy1, 0), 63);
        int o00 = (cy0 * 64 + cx0) * 64, o10 = (cy1 * 64 + cx0) * 64;
        int o01 = (cy0 * 64 + cx1) * 64, o11 = (cy1 * 64 + cx1) * 64;
        int c0 = cg * 8;
        bf16x8 aA = ld8(hbb + o00 + c0), aB = ld8(hbb + o10 + c0);
        bf16x8 aC = ld8(hbb + o01 + c0), aD = ld8(hbb + o11 + c0);
        #pragma unroll
        for (int i = 0; i < 8; ++i)
          ov.h[i] = (__bf16)(wA * (float)aA[i] + wB * (float)aB[i] +
                             wC * (float)aC[i] + wD * (float)aD[i]);
      }
      int G = l * 8 + cg;
      int Gs = (G & ~7) | ((G & 7) ^ (pxl & 7));
      *(bh8*)(wrp + (pxl * 40 + Gs) * 8) = ov;
    }
  }
  __syncthreads();

  // ret 1x1 GEMM (gate-block M-split) with 1-deep A-fragment ring
  f32x4 zv = {0.f, 0.f, 0.f, 0.f};
  f32x4 racc[3][2];
  #pragma unroll
  for (int mt = 0; mt < 3; ++mt)
    #pragma unroll
    for (int nt = 0; nt < 2; ++nt) racc[mt][nt] = zv;
  #pragma unroll
  for (int ks = 0; ks < 10; ++ks) {
    if (ks < 9) loadAr(ks + 1, nR);
    bf16x8 bfr[2];
    #pragma unroll
    for (int nt = 0; nt < 2; ++nt) {
      int pxl = nt * 16 + lr;
      int Gr = ks * 4 + q;
      int Gs = (Gr & ~7) | ((Gr & 7) ^ (pxl & 7));
      bfr[nt] = ld8(wrp + (pxl * 40 + Gs) * 8);
    }
    #pragma unroll
    for (int mt = 0; mt < 3; ++mt)
      #pragma unroll
      for (int nt = 0; nt < 2; ++nt)
        racc[mt][nt] = mfma16(cR[mt], bfr[nt], racc[mt][nt]);
    #pragma unroll
    for (int mt = 0; mt < 3; ++mt) cR[mt] = nR[mt];
  }

  // gates directly from accumulators
  #pragma unroll
  for (int nt = 0; nt < 2; ++nt) {
    int xg = x0 + nt * 16 + lr;
    float* ob = outp + (ll)b * osb + y * 64 + xg;
    float hn4[4];
    #pragma unroll
    for (int r = 0; r < 4; ++r) {
      int f = f0w + r;
      float hr = racc[0][nt][r] + br[f];
      float hu = racc[1][nt][r] + br[f + 64];
      float hm = racc[2][nt][r] + br[f + 128];
      float rr = 1.f / (1.f + __expf(-((float)irv[nt].h[r] + hr)));
      float uu = 1.f / (1.f + __expf(-((float)iuv[nt].h[r] + hu)));
      float m = lky((float)imv[nt].h[r] + rr * hm);
      float hn = uu * h04[nt][r] + (1.f - uu) * m;
      ob[(ll)f << 12] = hn;
      hn4[r] = hn;
    }
    st4(hbc + ((ll)(b * 64 + y) * 64 + xg) * 64 + f0w,
        hn4[0], hn4[1], hn4[2], hn4[3]);
  }
}

// Per-step kernels with y-octile XCD affinity (grid 1024).
__global__ __launch_bounds__(256, 6) void k_h2f5(
    int t0, const __bf16* hb, const __bf16* A, const float* bi, const float* bh,
    const __bf16* i2f_t, __bf16* f1buf) {
  __shared__ __align__(16) char smraw[H2F_SMEM_BYTES];
  int b, y, xh;
  step_decode(b, y, xh);
  dev_h2f(smraw, t0, hb, A, bi, bh, i2f_t, f1buf, b, y, xh);
}

__global__ __launch_bounds__(256, 4) void k_fwr2(
    int t0, const __bf16* f1buf, const __bf16* Afl, const float* bfl,
    const __bf16* hb, const __bf16* Aret, const float* br,
    const __bf16* i2h_t, const float* hprevf,
    float* outp, ll osb, __bf16* hbc) {
  __shared__ __align__(16) char smraw[FWR_SMEM_BYTES];
  int b, y, xh;
  step_decode(b, y, xh);
  dev_fwr(smraw, t0, f1buf, Afl, bfl, hb, Aret, br, i2h_t, hprevf,
          outp, osb, hbc, b, y, xh);
}

// ---------------------------------------------------------------------------
extern "C" void kernel_launch(void* const* d_in, const int* in_sizes, int n_in,
                              void* d_out, int out_size, void* d_ws, size_t ws_size,
                              hipStream_t stream) {
  const float* x      = (const float*)d_in[0];
  const float* W_down = (const float*)d_in[1];
  const float* b_down = (const float*)d_in[2];
  const float* W_i2h  = (const float*)d_in[3];
  const float* b_i2h  = (const float*)d_in[4];
  const float* W_i2f  = (const float*)d_in[5];
  const float* b_i2f  = (const float*)d_in[6];
  const float* W_h2f  = (const float*)d_in[7];
  const float* b_h2f  = (const float*)d_in[8];
  const float* W_flow = (const float*)d_in[9];
  const float* b_flow = (const float*)d_in[10];
  const float* W_ret  = (const float*)d_in[11];
  const float* b_ret  = (const float*)d_in[12];
  float* out = (float*)d_out;

  const ll H_N = (ll)NB * 4096 * 64;

  auto align256 = [](ll v) { return (v + 255) & ~255LL; };
  ll fixed = 0;
  fixed += align256(147456LL * 2);
  fixed += align256(110592LL * 2);
  fixed += align256(51200LL * 2) * 2;
  fixed += align256(12800LL * 2);
  fixed += align256(61440LL * 2);
  fixed += align256((ll)NT * NB * 4096 * 64 * 2);
  fixed += align256((ll)NB * 4096 * 32 * 2);
  fixed += align256(H_N * 2) * 2;
  ll need_full = fixed + align256(NT * I2H_T * 2) + align256(NT * I2F_T * 2);
  int fits = (need_full <= (ll)ws_size);
  int slabT = fits ? NT : 1;

  char* p = (char*)d_ws;
  auto alloc = [&](ll bytes) { char* r = p; p += (bytes + 255) & ~255LL; return r; };
  __bf16* Adown  = (__bf16*)alloc(147456LL * 2);
  __bf16* Ai2h   = (__bf16*)alloc(110592LL * 2);
  __bf16* Afi    = (__bf16*)alloc(51200LL * 2);
  __bf16* Afh    = (__bf16*)alloc(51200LL * 2);
  __bf16* Afl    = (__bf16*)alloc(12800LL * 2);
  __bf16* Aret   = (__bf16*)alloc(61440LL * 2);
  __bf16* seq    = (__bf16*)alloc((ll)NT * NB * 4096 * 64 * 2);
  __bf16* f1buf  = (__bf16*)alloc((ll)NB * 4096 * 32 * 2);
  __bf16* hbufA  = (__bf16*)alloc(H_N * 2);
  __bf16* hbufB  = (__bf16*)alloc(H_N * 2);
  __bf16* i2h_sl = (__bf16*)alloc(slabT * I2H_T * 2);
  __bf16* i2f_sl = (__bf16*)alloc(slabT * I2F_T * 2);
  if (p > (char*)d_ws + ws_size) return;

  k_prep<<<1698, 256, 0, stream>>>(W_down, W_i2h, W_i2f, W_h2f, W_flow, W_ret,
                                   Adown, Ai2h, Afi, Afh, Afl, Aret);
  k_down<<<NB * 64 * 4, 256, 0, stream>>>(x, Adown, b_down, seq);

  if (fits) {
    k_i2h4<<<NT * NB * 2 * 16, 256, 0, stream>>>(seq, Ai2h, b_i2h, i2h_sl);
    k_i2fb<<<NT * NB * 16, 256, 0, stream>>>(seq, Afi, i2f_sl);
  }

  const ll osb = (ll)NT * NF * HWSZ;
  for (int t = 0; t < NT; ++t) {
    const __bf16* xt0 = seq + (ll)t * NB * 4096 * 64;
    if (!fits) {
      k_i2h4<<<NB * 2 * 16, 256, 0, stream>>>(xt0, Ai2h, b_i2h, i2h_sl);
      k_i2fb<<<NB * 16, 256, 0, stream>>>(xt0, Afi, i2f_sl);
    }
    int ti = fits ? t : 0;
    const __bf16* hb = (t & 1) ? hbufA : hbufB;
    __bf16* hbc = (t & 1) ? hbufB : hbufA;
    const float* hpf = (t == 0) ? out : out + (ll)(t - 1) * NF * HWSZ;

    k_h2f5<<<NB * 64 * 2, 256, 0, stream>>>((t == 0) ? 1 : 0, hb, Afh,
                                            b_i2f, b_h2f,
                                            i2f_sl + (ll)ti * I2F_T, f1buf);
    k_fwr2<<<NB * 64 * 2, 256, 0, stream>>>((t == 0) ? 1 : 0, f1buf, Afl,
                                            b_flow, hb, Aret, b_ret,
                                            i2h_sl + (ll)ti * I2H_T, hpf,
                                            out + (ll)t * NF * HWSZ, osb, hbc);
  }
}

// Round 15
// 823.568 us; speedup vs baseline: 1.0193x; 1.0193x over previous
//
#include <hip/hip_runtime.h>
#include <cstdint>

typedef long long ll;
typedef __bf16 bf16x8 __attribute__((ext_vector_type(8)));
typedef float f32x4 __attribute__((ext_vector_type(4)));
typedef unsigned int u32x4 __attribute__((ext_vector_type(4)));

#define NB 8
#define NT 12
#define NF 64
#define HWSZ 4096
#define I2H_T ((ll)NB * 4096 * 192)
#define I2F_T ((ll)NB * 4096 * 32)

struct alignas(8)  bh4 { __bf16 h[4]; };
struct alignas(16) bh8 { __bf16 h[8]; };

static __device__ inline f32x4 mfma16(bf16x8 a, bf16x8 b, f32x4 c) {
  return __builtin_amdgcn_mfma_f32_16x16x32_bf16(a, b, c, 0, 0, 0);
}
static __device__ inline bf16x8 ld8(const __bf16* p) {
  u32x4 u = *(const u32x4*)p;
  return __builtin_bit_cast(bf16x8, u);
}
static __device__ inline void st4(__bf16* p, float a0, float a1, float a2, float a3) {
  bh4 t; t.h[0] = (__bf16)a0; t.h[1] = (__bf16)a1; t.h[2] = (__bf16)a2; t.h[3] = (__bf16)a3;
  *(bh4*)p = t;
}
static __device__ inline float lky(float a) { return a >= 0.f ? a : 0.2f * a; }

// XCD-chunked swizzle (grid divisible by 8): neighbors share an XCD L2.
static __device__ inline int swz_bid() {
  int bid = blockIdx.x;
  return ((gridDim.x & 7) == 0) ? (bid & 7) * (gridDim.x >> 3) + (bid >> 3) : bid;
}

// Step-kernel decode with y-octile XCD affinity.
static __device__ inline void step_decode(int& b, int& y, int& xh) {
  int bid = blockIdx.x;
  int oct = bid & 7, s = bid >> 3;
  b = s >> 4;
  int r = s & 15;
  y = oct * 8 + (r >> 1);
  xh = r & 1;
}

// Stage one row of a 64-ch NHWC bf16 map into LDS [g8][W][8] (full channels).
template<int W, int HALO>
static __device__ void stage8(__bf16* dst, const __bf16* grow) {
  int tid = threadIdx.x;
  u32x4 zz = {0u, 0u, 0u, 0u};
  #pragma unroll
  for (int it = 0; it < 2; ++it) {
    int i = tid + it * 256;
    int xr = i >> 3, g = i & 7, xi = xr + HALO;
    u32x4 v = zz;
    if (grow) v = *(const u32x4*)(grow + xr * 64 + g * 8);
    *(u32x4*)(dst + (g * W + xi) * 8) = v;
  }
  if (tid < 16 * HALO) {
    int h = tid >> 3, g = tid & 7;
    int xi = (h < HALO) ? h : 64 + h;
    *(u32x4*)(dst + (g * W + xi) * 8) = zz;
  }
}

// ---------------------------------------------------------------------------
// Weight pre-transform: bf16 fragment-friendly layouts.
__global__ __launch_bounds__(256) void k_prep(
    const float* __restrict__ Wd, const float* __restrict__ Wc,
    const float* __restrict__ Wi, const float* __restrict__ Wh,
    const float* __restrict__ Wfl, const float* __restrict__ Wret,
    __bf16* __restrict__ Adown, __bf16* __restrict__ Ai2h,
    __bf16* __restrict__ Afi, __bf16* __restrict__ Afh,
    __bf16* __restrict__ Afl, __bf16* __restrict__ Aret) {
  int n = blockIdx.x * 256 + threadIdx.x;
  if (n < 147456) {                            // Adown[oc][k]
    Adown[n] = (__bf16)Wd[n];
  } else if (n < 258048) {                     // Ai2h[tap][o192][c64]
    int i = n - 147456;
    int tap = i / 12288, o = (i % 12288) / 64, c = i % 64;
    Ai2h[i] = (__bf16)Wc[(o * 64 + c) * 9 + tap];
  } else if (n < 309248) {                     // Afi[tap][o32][c64]
    int i = n - 258048;
    int tap = i / 2048, o = (i % 2048) / 64, c = i % 64;
    Afi[i] = (__bf16)Wi[(o * 64 + c) * 25 + tap];
  } else if (n < 360448) {                     // Afh[tap][o32][c64]
    int i = n - 309248;
    int tap = i / 2048, o = (i % 2048) / 64, c = i % 64;
    Afh[i] = (__bf16)Wh[(o * 64 + c) * 25 + tap];
  } else if (n < 373248) {                     // Afl[tap][o16 pad][c32]
    int i = n - 360448;
    int tap = i / 512, o = (i % 512) / 32, c = i % 32;
    Afl[i] = (__bf16)(o < 10 ? Wfl[(o * 32 + c) * 25 + tap] : 0.f);
  } else if (n < 434688) {                     // Aret[o192][c320]
    Aret[n - 373248] = (__bf16)Wret[n - 373248];
  }
}

// ---------------------------------------------------------------------------
// Downsample conv as MFMA implicit GEMM. (b,y,zQ); zQ splits M=768 into 4.
__global__ __launch_bounds__(256) void k_down(
    const float* __restrict__ x, const __bf16* __restrict__ Adown,
    const float* __restrict__ bd, __bf16* __restrict__ seq) {
  __shared__ __bf16 smd[6240];
  int bi = swz_bid();
  int zQ = bi & 3, y = (bi >> 2) & 63, b = bi >> 8;
  int tid = threadIdx.x;
  for (int i = tid; i < 6240; i += 256) {
    int ic = i / 520, rem = i % 520, ky = rem / 130, xi = rem % 130;
    int ix = xi - 1, iy = 2 * y - 1 + ky;
    float v = (ix >= 0 && ix < 128 && iy >= 0 && iy < 128)
                  ? x[(((ll)(b * 12 + ic) * 128 + iy) << 7) + ix] : 0.f;
    smd[i] = (__bf16)v;
  }
  __syncthreads();
  int wv = __builtin_amdgcn_readfirstlane(tid >> 6);
  int lane = tid & 63, q = lane >> 4, lr = lane & 15;
  int px = wv * 16 + lr;
  f32x4 zv = {0.f, 0.f, 0.f, 0.f};
  f32x4 acc[12];
  #pragma unroll
  for (int mt = 0; mt < 12; ++mt) acc[mt] = zv;

  for (int ks = 0; ks < 6; ++ks) {
    int k0 = ks * 32 + q * 8;
    int ic = k0 >> 4, ky0 = (k0 >> 2) & 3;
    const __bf16* rp = smd + (ic * 4 + ky0) * 130 + 2 * px;
    bh8 bb;
    #pragma unroll
    for (int j = 0; j < 8; ++j)
      bb.h[j] = rp[(j >> 2) * 130 + (j & 3)];
    bf16x8 bfr = __builtin_bit_cast(bf16x8, bb);
    #pragma unroll
    for (int mt = 0; mt < 12; ++mt) {
      bf16x8 afr = ld8(Adown + ((ll)(zQ * 192 + mt * 16 + lr) * 192 + k0));
      acc[mt] = mfma16(afr, bfr, acc[mt]);
    }
  }
  #pragma unroll
  for (int mt = 0; mt < 12; ++mt) {
    int t_idx = zQ * 3 + (mt >> 2);
    int f0 = (mt & 3) * 16 + q * 4;
    float v[4];
    #pragma unroll
    for (int r = 0; r < 4; ++r)
      v[r] = lky(acc[mt][r] + bd[zQ * 192 + mt * 16 + q * 4 + r]);
    st4(seq + (((ll)(t_idx * NB + b) * 4096 + y * 64 + px) * 64 + f0),
        v[0], v[1], v[2], v[3]);
  }
}

// ---------------------------------------------------------------------------
// i2h 3x3 conv, A staged per-tap in double-buffered LDS + T5 setprio around
// the MFMA cluster (phase-split schedule -> scheduler has roles to arbitrate).
__global__ __launch_bounds__(256, 2) void k_i2h4(
    const __bf16* __restrict__ in0, const __bf16* __restrict__ A,
    const float* __restrict__ bc, __bf16* __restrict__ out0) {
  __shared__ __align__(16) __bf16 smI[6 * 8 * 67 * 8];
  __shared__ __align__(16) __bf16 smA[2][96 * 64];
  int bi_ = swz_bid();
  int yg = bi_ & 15, och = (bi_ >> 4) & 1, tb = bi_ >> 5;
  int y0 = yg * 4;
  const __bf16* base = in0 + (ll)tb * (4096 * 64);
  const __bf16* Ab = A + ((ll)och * 96) * 64;
  int tid = threadIdx.x;
  u32x4 ar[3];
  auto loadA = [&](int tap) {
    #pragma unroll
    for (int it = 0; it < 3; ++it) {
      int j = it * 256 + tid;
      ar[it] = *(const u32x4*)(Ab + (ll)tap * (192 * 64) + j * 8);
    }
  };
  auto writeA = [&](int buf) {
    #pragma unroll
    for (int it = 0; it < 3; ++it) {
      int j = it * 256 + tid;
      int oc = j >> 3, g = j & 7;
      *(u32x4*)(smA[buf] + oc * 64 + ((g ^ (oc & 7)) * 8)) = ar[it];
    }
  };
  loadA(0);
  #pragma unroll
  for (int s = 0; s < 6; ++s) {
    int yr = y0 - 1 + s;
    stage8<67, 1>(smI + s * (8 * 67 * 8),
                  (yr >= 0 && yr < 64) ? base + (ll)yr * 64 * 64 : nullptr);
  }
  writeA(0);
  __syncthreads();

  int wv = __builtin_amdgcn_readfirstlane(tid >> 6);
  int lane = tid & 63, q = lane >> 4, lr = lane & 15;
  int mh = wv & 1, rg = wv >> 1;
  f32x4 zv = {0.f, 0.f, 0.f, 0.f};
  f32x4 acc[3][8];
  #pragma unroll
  for (int mt = 0; mt < 3; ++mt)
    #pragma unroll
    for (int nt = 0; nt < 8; ++nt) acc[mt][nt] = zv;

  for (int tap = 0; tap < 9; ++tap) {
    if (tap < 8) loadA(tap + 1);            // issue early (T14)
    int ky = tap / 3, kx = tap % 3;
    const __bf16* Ax = smA[tap & 1];
    __builtin_amdgcn_s_setprio(1);          // T5: favor MFMA-entering waves
    #pragma unroll
    for (int ks = 0; ks < 2; ++ks) {
      bf16x8 afr[3];
      #pragma unroll
      for (int mt = 0; mt < 3; ++mt) {
        int oc = mh * 48 + mt * 16 + lr;
        afr[mt] = ld8(Ax + oc * 64 + (((ks * 4 + q) ^ (lr & 7)) * 8));
      }
      bf16x8 bfr[8];
      #pragma unroll
      for (int rl = 0; rl < 2; ++rl)
        #pragma unroll
        for (int nx = 0; nx < 4; ++nx) {
          int s = rg * 2 + rl + ky;
          bfr[rl * 4 + nx] =
              ld8(smI + ((s * 8 + ks * 4 + q) * 67 + nx * 16 + lr + kx) * 8);
        }
      #pragma unroll
      for (int mt = 0; mt < 3; ++mt)
        #pragma unroll
        for (int nt = 0; nt < 8; ++nt)
          acc[mt][nt] = mfma16(afr[mt], bfr[nt], acc[mt][nt]);
    }
    __builtin_amdgcn_s_setprio(0);
    if (tap < 8) writeA((tap + 1) & 1);     // write late
    __syncthreads();
  }

  #pragma unroll
  for (int rl = 0; rl < 2; ++rl)
    #pragma unroll
    for (int nx = 0; nx < 4; ++nx) {
      int row = y0 + rg * 2 + rl, px = nx * 16 + lr;
      __bf16* op = out0 + ((ll)tb * 4096 + row * 64 + px) * 192;
      #pragma unroll
      for (int mt = 0; mt < 3; ++mt) {
        int oc0 = och * 96 + mh * 48 + mt * 16 + q * 4;
        f32x4 a = acc[mt][rl * 4 + nx];
        st4(op + oc0, a[0] + bc[oc0], a[1] + bc[oc0 + 1],
                      a[2] + bc[oc0 + 2], a[3] + bc[oc0 + 3]);
      }
    }
}

// ---------------------------------------------------------------------------
// Batched i2f 5x5 (no bias) + T5 setprio around per-tap MFMA cluster.
__global__ __launch_bounds__(256, 2) void k_i2fb(
    const __bf16* __restrict__ in0, const __bf16* __restrict__ A,
    __bf16* __restrict__ out0) {
  __shared__ __align__(16) __bf16 smI[8 * 8 * 69 * 8];
  __shared__ __align__(16) __bf16 smA[2][32 * 64];
  float* red = (float*)smI;
  int bi_ = swz_bid();
  int yg = bi_ & 15, tb = bi_ >> 4;
  int y0 = yg * 4;
  const __bf16* base = in0 + (ll)tb * (4096 * 64);
  int tid = threadIdx.x;
  u32x4 ar;
  auto loadA = [&](int tap) { ar = *(const u32x4*)(A + (ll)tap * 2048 + tid * 8); };
  auto writeA = [&](int buf) {
    int oc = tid >> 3, g = tid & 7;
    *(u32x4*)(smA[buf] + oc * 64 + ((g ^ (oc & 7)) * 8)) = ar;
  };
  loadA(0);
  #pragma unroll
  for (int s = 0; s < 8; ++s) {
    int yr = y0 - 2 + s;
    stage8<69, 2>(smI + s * (8 * 69 * 8),
                  (yr >= 0 && yr < 64) ? base + (ll)yr * 64 * 64 : nullptr);
  }
  writeA(0);
  __syncthreads();

  int wv = __builtin_amdgcn_readfirstlane(tid >> 6);
  int lane = tid & 63, q = lane >> 4, lr = lane & 15;
  int rg = wv & 1, ksh = wv >> 1;
  f32x4 zv = {0.f, 0.f, 0.f, 0.f};
  f32x4 acc[2][8];
  #pragma unroll
  for (int mt = 0; mt < 2; ++mt)
    #pragma unroll
    for (int nt = 0; nt < 8; ++nt) acc[mt][nt] = zv;

  for (int tap = 0; tap < 25; ++tap) {
    if (tap < 24) loadA(tap + 1);
    int ky = tap / 5, kx = tap % 5;
    const __bf16* Ax = smA[tap & 1];
    __builtin_amdgcn_s_setprio(1);          // T5
    bf16x8 afr[2];
    #pragma unroll
    for (int mt = 0; mt < 2; ++mt) {
      int oc = mt * 16 + lr;
      afr[mt] = ld8(Ax + oc * 64 + (((ksh * 4 + q) ^ (lr & 7)) * 8));
    }
    bf16x8 bfr[8];
    #pragma unroll
    for (int rl = 0; rl < 2; ++rl)
      #pragma unroll
      for (int nx = 0; nx < 4; ++nx) {
        int s = rg * 2 + rl + ky;
        bfr[rl * 4 + nx] =
            ld8(smI + ((s * 8 + ksh * 4 + q) * 69 + nx * 16 + lr + kx) * 8);
      }
    #pragma unroll
    for (int mt = 0; mt < 2; ++mt)
      #pragma unroll
      for (int nt = 0; nt < 8; ++nt)
        acc[mt][nt] = mfma16(afr[mt], bfr[nt], acc[mt][nt]);
    __builtin_amdgcn_s_setprio(0);
    if (tap < 24) writeA((tap + 1) & 1);
    __syncthreads();
  }

  if (ksh == 1) {
    #pragma unroll
    for (int mt = 0; mt < 2; ++mt)
      #pragma unroll
      for (int rl = 0; rl < 2; ++rl)
        #pragma unroll
        for (int nx = 0; nx < 4; ++nx) {
          int row_l = rg * 2 + rl, px = nx * 16 + lr;
          int oc = mt * 16 + q * 4;
          f32x4 a = acc[mt][rl * 4 + nx];
          #pragma unroll
          for (int r = 0; r < 4; ++r)
            red[(row_l * 64 + px) * 33 + oc + r] = a[r];
        }
  }
  __syncthreads();
  if (ksh == 0) {
    #pragma unroll
    for (int mt = 0; mt < 2; ++mt)
      #pragma unroll
      for (int rl = 0; rl < 2; ++rl)
        #pragma unroll
        for (int nx = 0; nx < 4; ++nx) {
          int row_l = rg * 2 + rl, px = nx * 16 + lr;
          int oc0 = mt * 16 + q * 4;
          f32x4 a = acc[mt][rl * 4 + nx];
          float v[4];
          #pragma unroll
          for (int r = 0; r < 4; ++r)
            v[r] = a[r] + red[(row_l * 64 + px) * 33 + oc0 + r];
          st4(out0 + ((ll)tb * 4096 + (y0 + row_l) * 64 + px) * 32 + oc0,
              v[0], v[1], v[2], v[3]);
        }
  }
}

// ---------------------------------------------------------------------------
// Step-phase device functions (exact R13). Shared LDS region: 27520 B.
#define STEP_SMEM_BYTES (25344 + 2176)

static __device__ void dev_h2f(char* smraw, int t0,
    const __bf16* __restrict__ hb, const __bf16* __restrict__ A,
    const float* __restrict__ bi, const float* __restrict__ bh,
    const __bf16* __restrict__ i2f_t, __bf16* __restrict__ f1buf,
    int b, int y, int xh) {
  __bf16* smI = (__bf16*)smraw;
  float* red = (float*)smraw;
  int x0 = xh * 32;
  int tid = threadIdx.x;
  int wv = __builtin_amdgcn_readfirstlane(tid >> 6);
  int lane = tid & 63, q = lane >> 4, lr = lane & 15;

  int pxl_e = tid >> 3, oc0_e = (tid & 7) * 4;
  bh4 iv = *(const bh4*)(i2f_t + ((ll)(b * 64 + y) * 64 + x0 + pxl_e) * 32 + oc0_e);

  bf16x8 cur[2][2], nxt[2][2];
  auto loadAt = [&](int tap, bf16x8 a[2][2]) {
    #pragma unroll
    for (int ks = 0; ks < 2; ++ks)
      #pragma unroll
      for (int mt = 0; mt < 2; ++mt)
        a[ks][mt] = ld8(A + ((ll)(tap * 32 + mt * 16 + lr) * 64 + ks * 32 + q * 8));
  };
  loadAt(wv, cur);

  u32x4 zz = {0u, 0u, 0u, 0u};
  for (int i = tid; i < 5 * 296; i += 256) {
    int s = i / 296, rem = i % 296, xi = rem >> 3, g = rem & 7;
    int yr = y - 2 + s, xg = x0 - 2 + xi;
    u32x4 v = zz;
    if (!t0 && yr >= 0 && yr < 64 && xg >= 0 && xg < 64)
      v = *(const u32x4*)(hb + ((ll)(b * 64 + yr) * 64 + xg) * 64 + g * 8);
    *(u32x4*)(smI + ((s * 8 + g) * 37 + xi) * 8) = v;
  }
  __syncthreads();

  f32x4 zv = {0.f, 0.f, 0.f, 0.f};
  f32x4 acc[2][2];
  #pragma unroll
  for (int mt = 0; mt < 2; ++mt)
    #pragma unroll
    for (int nx = 0; nx < 2; ++nx) acc[mt][nx] = zv;

  #pragma unroll
  for (int j = 0; j < 7; ++j) {
    int tap = 4 * j + wv;
    if (tap < 25) {
      if (tap + 4 < 25) loadAt(tap + 4, nxt);
      int ky = tap / 5, kx = tap % 5;
      #pragma unroll
      for (int ks = 0; ks < 2; ++ks) {
        bf16x8 bfr[2];
        #pragma unroll
        for (int nx = 0; nx < 2; ++nx)
          bfr[nx] = ld8(smI + ((ky * 8 + ks * 4 + q) * 37 + nx * 16 + lr + kx) * 8);
        #pragma unroll
        for (int mt = 0; mt < 2; ++mt)
          #pragma unroll
          for (int nx = 0; nx < 2; ++nx)
            acc[mt][nx] = mfma16(cur[ks][mt], bfr[nx], acc[mt][nx]);
      }
      #pragma unroll
      for (int ks = 0; ks < 2; ++ks)
        #pragma unroll
        for (int mt = 0; mt < 2; ++mt) cur[ks][mt] = nxt[ks][mt];
    }
  }
  __syncthreads();

  #pragma unroll
  for (int mt = 0; mt < 2; ++mt)
    #pragma unroll
    for (int nx = 0; nx < 2; ++nx) {
      int pxl = nx * 16 + lr, oc = mt * 16 + q * 4;
      f32x4 a = acc[mt][nx];
      #pragma unroll
      for (int r = 0; r < 4; ++r)
        red[wv * 1056 + pxl * 33 + oc + r] = a[r];
    }
  __syncthreads();

  float v[4];
  #pragma unroll
  for (int r = 0; r < 4; ++r) {
    float s = red[0 * 1056 + pxl_e * 33 + oc0_e + r] + red[1 * 1056 + pxl_e * 33 + oc0_e + r] +
              red[2 * 1056 + pxl_e * 33 + oc0_e + r] + red[3 * 1056 + pxl_e * 33 + oc0_e + r];
    v[r] = lky(s + (float)iv.h[r] + bi[oc0_e + r] + bh[oc0_e + r]);
  }
  st4(f1buf + ((ll)(b * 64 + y) * 64 + x0 + pxl_e) * 32 + oc0_e, v[0], v[1], v[2], v[3]);
}

// fwr with GATE-BLOCK M-split (R13): wave w owns oc rows {w*16,64+w*16,128+w*16};
// lane acc[0/1/2] = (hr,hu,hm) triplet for f=w*16+q*4+r at px=nt*16+lr.
static __device__ void dev_fwr(char* smraw, int t0,
    const __bf16* __restrict__ f1buf, const __bf16* __restrict__ Afl,
    const float* __restrict__ bfl, const __bf16* __restrict__ hb,
    const __bf16* __restrict__ Aret, const float* __restrict__ br,
    const __bf16* __restrict__ i2h_t, const float* __restrict__ hprevf,
    float* __restrict__ outp, ll osb, __bf16* __restrict__ hbc,
    int b, int y, int xh) {
  float* flows = (float*)(smraw + 25344);
  __bf16* f1l = (__bf16*)smraw;
  __bf16* wrp = (__bf16*)smraw;
  int x0 = xh * 32;
  int tid = threadIdx.x;
  int wv = __builtin_amdgcn_readfirstlane(tid >> 6);
  int lane = tid & 63, q = lane >> 4, lr = lane & 15;

  // hoisted gate inputs (cold -> issue first)
  int f0w = wv * 16 + q * 4;
  bh4 irv[2], iuv[2], imv[2];
  float h04[2][4];
  #pragma unroll
  for (int nt = 0; nt < 2; ++nt) {
    int xg = x0 + nt * 16 + lr;
    const __bf16* ih = i2h_t + ((ll)(b * 64 + y) * 64 + xg) * 192;
    irv[nt] = *(const bh4*)(ih + f0w);
    iuv[nt] = *(const bh4*)(ih + 64 + f0w);
    imv[nt] = *(const bh4*)(ih + 128 + f0w);
    const float* hp = hprevf + (ll)b * osb + y * 64 + xg;
    #pragma unroll
    for (int r = 0; r < 4; ++r)
      h04[nt][r] = t0 ? 0.f : hp[(ll)(f0w + r) << 12];
  }

  u32x4 zz = {0u, 0u, 0u, 0u};
  for (int i = tid; i < 5 * 148; i += 256) {
    int s = i / 148, rem = i % 148, xi = rem >> 2, g = rem & 3;
    int yr = y - 2 + s, xg = x0 - 2 + xi;
    u32x4 v = zz;
    if (yr >= 0 && yr < 64 && xg >= 0 && xg < 64)
      v = *(const u32x4*)(f1buf + ((ll)(b * 64 + yr) * 64 + xg) * 32 + g * 8);
    *(u32x4*)(f1l + ((s * 4 + g) * 37 + xi) * 8) = v;
  }
  __syncthreads();

  if (wv < 2) {
    f32x4 acc1 = {0.f, 0.f, 0.f, 0.f};
    #pragma unroll
    for (int tap = 0; tap < 25; ++tap) {
      int ky = tap / 5, kx = tap % 5;
      bf16x8 bfr = ld8(f1l + ((ky * 4 + q) * 37 + wv * 16 + lr + kx) * 8);
      bf16x8 afr = ld8(Afl + ((ll)(tap * 16 + lr) * 32 + q * 8));
      acc1 = mfma16(afr, bfr, acc1);
    }
    #pragma unroll
    for (int r = 0; r < 4; ++r) {
      int oc = q * 4 + r;
      flows[(wv * 16 + lr) * 17 + oc] = acc1[r] + (oc < 10 ? bfl[oc] : 0.f);
    }
  }
  __syncthreads();

  // issue first Aret fragments before warp so L2 latency hides under it
  bf16x8 cR[3], nR[3];
  auto loadAr = [&](int ks, bf16x8* a) {
    #pragma unroll
    for (int mt = 0; mt < 3; ++mt)
      a[mt] = ld8(Aret + ((ll)(mt * 64 + wv * 16 + lr) * 320 + ks * 32 + q * 8));
  };
  loadAr(0, cR);

  {
    int pxl = tid & 31, cg = tid >> 5;
    int xw = x0 + pxl;
    const __bf16* hbb = hb + ((ll)b << 18);
    #pragma unroll
    for (int l = 0; l < 5; ++l) {
      bh8 ov;
      if (t0) {
        #pragma unroll
        for (int i = 0; i < 8; ++i) ov.h[i] = (__bf16)0.f;
      } else {
        float fx = flows[pxl * 17 + 2 * l];
        float fy = flows[pxl * 17 + 2 * l + 1];
        float pxf = (float)xw - fx, pyf = (float)y - fy;
        float x0f = floorf(pxf), y0f = floorf(pyf);
        int xx0 = (int)x0f, yy0 = (int)y0f, xx1 = xx0 + 1, yy1 = yy0 + 1;
        float dx = pxf - x0f, dy = pyf - y0f;
        bool vx0 = xx0 >= 0 && xx0 <= 63, vx1 = xx1 >= 0 && xx1 <= 63;
        bool vy0 = yy0 >= 0 && yy0 <= 63, vy1 = yy1 >= 0 && yy1 <= 63;
        float wA = (vx0 && vy0) ? (1.f - dx) * (1.f - dy) : 0.f;
        float wB = (vx0 && vy1) ? (1.f - dx) * dy : 0.f;
        float wC = (vx1 && vy0) ? dx * (1.f - dy) : 0.f;
        float wD = (vx1 && vy1) ? dx * dy : 0.f;
        int cx0 = min(max(xx0, 0), 63), cx1 = min(max(xx1, 0), 63);
        int cy0 = min(max(yy0, 0), 63), cy1 = min(max(yy1, 0), 63);
        int o00 = (cy0 * 64 + cx0) * 64, o10 = (cy1 * 64 + cx0) * 64;
        int o01 = (cy0 * 64 + cx1) * 64, o11 = (cy1 * 64 + cx1) * 64;
        int c0 = cg * 8;
        bf16x8 aA = ld8(hbb + o00 + c0), aB = ld8(hbb + o10 + c0);
        bf16x8 aC = ld8(hbb + o01 + c0), aD = ld8(hbb + o11 + c0);
        #pragma unroll
        for (int i = 0; i < 8; ++i)
          ov.h[i] = (__bf16)(wA * (float)aA[i] + wB * (float)aB[i] +
                             wC * (float)aC[i] + wD * (float)aD[i]);
      }
      int G = l * 8 + cg;
      int Gs = (G & ~7) | ((G & 7) ^ (pxl & 7));
      *(bh8*)(wrp + (pxl * 40 + Gs) * 8) = ov;
    }
  }
  __syncthreads();

  // ret 1x1 GEMM (gate-block M-split) with 1-deep A-fragment ring
  f32x4 zv = {0.f, 0.f, 0.f, 0.f};
  f32x4 racc[3][2];
  #pragma unroll
  for (int mt = 0; mt < 3; ++mt)
    #pragma unroll
    for (int nt = 0; nt < 2; ++nt) racc[mt][nt] = zv;
  #pragma unroll
  for (int ks = 0; ks < 10; ++ks) {
    if (ks < 9) loadAr(ks + 1, nR);
    bf16x8 bfr[2];
    #pragma unroll
    for (int nt = 0; nt < 2; ++nt) {
      int pxl = nt * 16 + lr;
      int Gr = ks * 4 + q;
      int Gs = (Gr & ~7) | ((Gr & 7) ^ (pxl & 7));
      bfr[nt] = ld8(wrp + (pxl * 40 + Gs) * 8);
    }
    #pragma unroll
    for (int mt = 0; mt < 3; ++mt)
      #pragma unroll
      for (int nt = 0; nt < 2; ++nt)
        racc[mt][nt] = mfma16(cR[mt], bfr[nt], racc[mt][nt]);
    #pragma unroll
    for (int mt = 0; mt < 3; ++mt) cR[mt] = nR[mt];
  }

  // gates directly from accumulators (no exchange, no barriers)
  #pragma unroll
  for (int nt = 0; nt < 2; ++nt) {
    int xg = x0 + nt * 16 + lr;
    float* ob = outp + (ll)b * osb + y * 64 + xg;
    float hn4[4];
    #pragma unroll
    for (int r = 0; r < 4; ++r) {
      int f = f0w + r;
      float hr = racc[0][nt][r] + br[f];
      float hu = racc[1][nt][r] + br[f + 64];
      float hm = racc[2][nt][r] + br[f + 128];
      float rr = 1.f / (1.f + __expf(-((float)irv[nt].h[r] + hr)));
      float uu = 1.f / (1.f + __expf(-((float)iuv[nt].h[r] + hu)));
      float m = lky((float)imv[nt].h[r] + rr * hm);
      float hn = uu * h04[nt][r] + (1.f - uu) * m;
      ob[(ll)f << 12] = hn;
      hn4[r] = hn;
    }
    st4(hbc + ((ll)(b * 64 + y) * 64 + xg) * 64 + f0w,
        hn4[0], hn4[1], hn4[2], hn4[3]);
  }
}

// Per-step kernels with y-octile XCD affinity (grid 1024).
__global__ __launch_bounds__(256, 4) void k_h2f5(
    int t0, const __bf16* hb, const __bf16* A, const float* bi, const float* bh,
    const __bf16* i2f_t, __bf16* f1buf) {
  __shared__ __align__(16) char smraw[STEP_SMEM_BYTES];
  int b, y, xh;
  step_decode(b, y, xh);
  dev_h2f(smraw, t0, hb, A, bi, bh, i2f_t, f1buf, b, y, xh);
}

__global__ __launch_bounds__(256, 4) void k_fwr2(
    int t0, const __bf16* f1buf, const __bf16* Afl, const float* bfl,
    const __bf16* hb, const __bf16* Aret, const float* br,
    const __bf16* i2h_t, const float* hprevf,
    float* outp, ll osb, __bf16* hbc) {
  __shared__ __align__(16) char smraw[STEP_SMEM_BYTES];
  int b, y, xh;
  step_decode(b, y, xh);
  dev_fwr(smraw, t0, f1buf, Afl, bfl, hb, Aret, br, i2h_t, hprevf,
          outp, osb, hbc, b, y, xh);
}

// ---------------------------------------------------------------------------
extern "C" void kernel_launch(void* const* d_in, const int* in_sizes, int n_in,
                              void* d_out, int out_size, void* d_ws, size_t ws_size,
                              hipStream_t stream) {
  const float* x      = (const float*)d_in[0];
  const float* W_down = (const float*)d_in[1];
  const float* b_down = (const float*)d_in[2];
  const float* W_i2h  = (const float*)d_in[3];
  const float* b_i2h  = (const float*)d_in[4];
  const float* W_i2f  = (const float*)d_in[5];
  const float* b_i2f  = (const float*)d_in[6];
  const float* W_h2f  = (const float*)d_in[7];
  const float* b_h2f  = (const float*)d_in[8];
  const float* W_flow = (const float*)d_in[9];
  const float* b_flow = (const float*)d_in[10];
  const float* W_ret  = (const float*)d_in[11];
  const float* b_ret  = (const float*)d_in[12];
  float* out = (float*)d_out;

  const ll H_N = (ll)NB * 4096 * 64;

  auto align256 = [](ll v) { return (v + 255) & ~255LL; };
  ll fixed = 0;
  fixed += align256(147456LL * 2);
  fixed += align256(110592LL * 2);
  fixed += align256(51200LL * 2) * 2;
  fixed += align256(12800LL * 2);
  fixed += align256(61440LL * 2);
  fixed += align256((ll)NT * NB * 4096 * 64 * 2);
  fixed += align256((ll)NB * 4096 * 32 * 2);
  fixed += align256(H_N * 2) * 2;
  ll need_full = fixed + align256(NT * I2H_T * 2) + align256(NT * I2F_T * 2);
  int fits = (need_full <= (ll)ws_size);
  int slabT = fits ? NT : 1;

  char* p = (char*)d_ws;
  auto alloc = [&](ll bytes) { char* r = p; p += (bytes + 255) & ~255LL; return r; };
  __bf16* Adown  = (__bf16*)alloc(147456LL * 2);
  __bf16* Ai2h   = (__bf16*)alloc(110592LL * 2);
  __bf16* Afi    = (__bf16*)alloc(51200LL * 2);
  __bf16* Afh    = (__bf16*)alloc(51200LL * 2);
  __bf16* Afl    = (__bf16*)alloc(12800LL * 2);
  __bf16* Aret   = (__bf16*)alloc(61440LL * 2);
  __bf16* seq    = (__bf16*)alloc((ll)NT * NB * 4096 * 64 * 2);
  __bf16* f1buf  = (__bf16*)alloc((ll)NB * 4096 * 32 * 2);
  __bf16* hbufA  = (__bf16*)alloc(H_N * 2);
  __bf16* hbufB  = (__bf16*)alloc(H_N * 2);
  __bf16* i2h_sl = (__bf16*)alloc(slabT * I2H_T * 2);
  __bf16* i2f_sl = (__bf16*)alloc(slabT * I2F_T * 2);
  if (p > (char*)d_ws + ws_size) return;

  k_prep<<<1698, 256, 0, stream>>>(W_down, W_i2h, W_i2f, W_h2f, W_flow, W_ret,
                                   Adown, Ai2h, Afi, Afh, Afl, Aret);
  k_down<<<NB * 64 * 4, 256, 0, stream>>>(x, Adown, b_down, seq);

  if (fits) {
    k_i2h4<<<NT * NB * 2 * 16, 256, 0, stream>>>(seq, Ai2h, b_i2h, i2h_sl);
    k_i2fb<<<NT * NB * 16, 256, 0, stream>>>(seq, Afi, i2f_sl);
  }

  const ll osb = (ll)NT * NF * HWSZ;
  for (int t = 0; t < NT; ++t) {
    const __bf16* xt0 = seq + (ll)t * NB * 4096 * 64;
    if (!fits) {
      k_i2h4<<<NB * 2 * 16, 256, 0, stream>>>(xt0, Ai2h, b_i2h, i2h_sl);
      k_i2fb<<<NB * 16, 256, 0, stream>>>(xt0, Afi, i2f_sl);
    }
    int ti = fits ? t : 0;
    const __bf16* hb = (t & 1) ? hbufA : hbufB;
    __bf16* hbc = (t & 1) ? hbufB : hbufA;
    const float* hpf = (t == 0) ? out : out + (ll)(t - 1) * NF * HWSZ;

    k_h2f5<<<NB * 64 * 2, 256, 0, stream>>>((t == 0) ? 1 : 0, hb, Afh,
                                            b_i2f, b_h2f,
                                            i2f_sl + (ll)ti * I2F_T, f1buf);
    k_fwr2<<<NB * 64 * 2, 256, 0, stream>>>((t == 0) ? 1 : 0, f1buf, Afl,
                                            b_flow, hb, Aret, b_ret,
                                            i2h_sl + (ll)ti * I2H_T, hpf,
                                            out + (ll)t * NF * HWSZ, osb, hbc);
  }
}